// Round 5
// baseline (1507.790 us; speedup 1.0000x reference)
//
#include <hip/hip_runtime.h>
#include <hip/hip_bf16.h>

#define BB 64
#define LL 512
#define DD 256
#define VV 32000
#define KK 6
#define HH 4
#define FF 512
#define MM (BB * LL)

typedef __hip_bfloat16 bf16;
typedef unsigned short ushort_t;
typedef __attribute__((ext_vector_type(8))) __bf16 bf16x8;
typedef __attribute__((ext_vector_type(4))) float f32x4;
#define MFMA __builtin_amdgcn_mfma_f32_16x16x32_bf16

__device__ __forceinline__ ushort_t f2bfbits(float x) {
  return __builtin_bit_cast(unsigned short, (__bf16)x);
}
__device__ __forceinline__ unsigned pkbf(float lo, float hi) {
  return (unsigned)f2bfbits(lo) | ((unsigned)f2bfbits(hi) << 16);
}
union U8 { unsigned u[4]; bf16x8 v; };

// async global->LDS, 16B/lane; dest must be WAVE-UNIFORM base (HW adds lane*16)
__device__ __forceinline__ void gl_lds16(const ushort_t* g, ushort_t* l) {
  __builtin_amdgcn_global_load_lds(
      (const __attribute__((address_space(1))) unsigned int*)g,
      (__attribute__((address_space(3))) unsigned int*)l, 16, 0, 0);
}

__device__ __forceinline__ float blk_sum(float v, float* red) {
  #pragma unroll
  for (int o = 32; o > 0; o >>= 1) v += __shfl_down(v, o, 64);
  __syncthreads();
  if ((threadIdx.x & 63) == 0) red[threadIdx.x >> 6] = v;
  __syncthreads();
  return red[0] + red[1] + red[2] + red[3];
}

__global__ __launch_bounds__(256) void k_lens(const int* __restrict__ tokens, int* __restrict__ lens) {
  __shared__ float red[4];
  int b = blockIdx.x, t = threadIdx.x;
  float c = (tokens[b * LL + t] != 0 ? 1.f : 0.f) + (tokens[b * LL + 256 + t] != 0 ? 1.f : 0.f);
  float s = blk_sum(c, red);
  if (t == 0) lens[b] = (int)(s + 0.5f);
}

__global__ __launch_bounds__(256) void k_embed4(const int* __restrict__ tokens,
                                                const float* __restrict__ tok_emb,
                                                const float* __restrict__ pos_emb,
                                                const float* __restrict__ g,
                                                const float* __restrict__ be,
                                                float* __restrict__ X) {
  int wid = threadIdx.x >> 6, lane = threadIdx.x & 63;
  int row = blockIdx.x * 4 + wid;
  int l = row & (LL - 1);
  int tok = tokens[row];
  float4 a = *reinterpret_cast<const float4*>(tok_emb + (size_t)tok * DD + lane * 4);
  float4 p = *reinterpret_cast<const float4*>(pos_emb + (size_t)l * DD + lane * 4);
  float4 v = {a.x + p.x, a.y + p.y, a.z + p.z, a.w + p.w};
  float s = v.x + v.y + v.z + v.w;
  float q = v.x * v.x + v.y * v.y + v.z * v.z + v.w * v.w;
  #pragma unroll
  for (int o = 32; o > 0; o >>= 1) { s += __shfl_xor(s, o, 64); q += __shfl_xor(q, o, 64); }
  float mu = s * (1.f / DD);
  float rstd = rsqrtf(q * (1.f / DD) - mu * mu + 1e-5f);
  float4 gv = *reinterpret_cast<const float4*>(g + lane * 4);
  float4 bv = *reinterpret_cast<const float4*>(be + lane * 4);
  float4 o4 = {(v.x - mu) * rstd * gv.x + bv.x, (v.y - mu) * rstd * gv.y + bv.y,
               (v.z - mu) * rstd * gv.z + bv.z, (v.w - mu) * rstd * gv.w + bv.w};
  *reinterpret_cast<float4*>(X + (size_t)row * DD + lane * 4) = o4;
}

__global__ __launch_bounds__(256) void k_ln4(const float* __restrict__ X,
                                             const float* __restrict__ g,
                                             const float* __restrict__ be,
                                             const int* __restrict__ lens,
                                             bf16* __restrict__ H) {
  int wid = threadIdx.x >> 6, lane = threadIdx.x & 63;
  int row = blockIdx.x * 4 + wid;
  int b = row >> 9, l = row & (LL - 1);
  if (l >= lens[b]) return;
  float4 v = *reinterpret_cast<const float4*>(X + (size_t)row * DD + lane * 4);
  float s = v.x + v.y + v.z + v.w;
  float q = v.x * v.x + v.y * v.y + v.z * v.z + v.w * v.w;
  #pragma unroll
  for (int o = 32; o > 0; o >>= 1) { s += __shfl_xor(s, o, 64); q += __shfl_xor(q, o, 64); }
  float mu = s * (1.f / DD);
  float rstd = rsqrtf(q * (1.f / DD) - mu * mu + 1e-5f);
  float4 gv = *reinterpret_cast<const float4*>(g + lane * 4);
  float4 bv = *reinterpret_cast<const float4*>(be + lane * 4);
  ushort4 o4;
  o4.x = f2bfbits((v.x - mu) * rstd * gv.x + bv.x);
  o4.y = f2bfbits((v.y - mu) * rstd * gv.y + bv.y);
  o4.z = f2bfbits((v.z - mu) * rstd * gv.z + bv.z);
  o4.w = f2bfbits((v.w - mu) * rstd * gv.w + bv.w);
  *reinterpret_cast<ushort4*>((ushort_t*)H + (size_t)row * DD + lane * 4) = o4;
}

__global__ __launch_bounds__(256) void k_cvt(const float* __restrict__ s, ushort_t* __restrict__ d, int n) {
  int i = (blockIdx.x * 256 + threadIdx.x) * 4;
  if (i >= n) return;
  float4 v = *reinterpret_cast<const float4*>(s + i);
  ushort4 o;
  o.x = f2bfbits(v.x); o.y = f2bfbits(v.y); o.z = f2bfbits(v.z); o.w = f2bfbits(v.w);
  *reinterpret_cast<ushort4*>(d + i) = o;
}

__global__ __launch_bounds__(256) void k_cvtw(const float* __restrict__ w0, const float* __restrict__ w1,
                                              const float* __restrict__ w2, const float* __restrict__ w3,
                                              ushort_t* __restrict__ d) {
  int i = (blockIdx.x * 256 + threadIdx.x) * 4;
  const float* s; int off;
  if (i < 196608)      { s = w0; off = i; }
  else if (i < 262144) { s = w1; off = i - 196608; }
  else if (i < 393216) { s = w2; off = i - 262144; }
  else                 { s = w3; off = i - 393216; }
  float4 v = *reinterpret_cast<const float4*>(s + off);
  ushort4 o;
  o.x = f2bfbits(v.x); o.y = f2bfbits(v.y); o.z = f2bfbits(v.z); o.w = f2bfbits(v.w);
  *reinterpret_cast<ushort4*>(d + i) = o;
}

// -------- MFMA GEMM v3: tile 128m x 256n, BK=32, 4 waves (wave = 64x128) --------
// OMODE: 0 = f32 out1, 1 = bf16 out1, 2 = QKV split (cols<512 -> QK[m][512], else VT[b][h][d][k])
template <int OMODE, bool GELU, bool RES>
__global__ __launch_bounds__(256, 2) void k_mgemm(const ushort_t* __restrict__ A,
                                                  const ushort_t* __restrict__ Wb,
                                                  const float* __restrict__ bias,
                                                  const float* __restrict__ res,
                                                  void* __restrict__ out1,
                                                  ushort_t* __restrict__ out2,
                                                  const int* __restrict__ lens,
                                                  int M, int Ndim, int Kdim) {
  int n0 = blockIdx.x * 256, m0 = blockIdx.y * 128;
  if (M > 128) {
    if ((m0 & (LL - 1)) >= lens[m0 >> 9]) return;
  }
  __shared__ __align__(16) ushort_t As[2][4096];
  __shared__ __align__(16) ushort_t Bs[2][8192];
  int t = threadIdx.x, lane = t & 63, w = t >> 6;
  int wr = (w >> 1) * 64, wc = (w & 1) * 128;
  int fr = lane & 15, fg = lane >> 4;

  // staging sources (dest rows = local; swizzle uses LOCAL row, source row clamped)
  int sra0 = t >> 2, sra1 = 64 + (t >> 2);
  int ca = lane & 3;
  int ga0 = m0 + sra0; if (ga0 > M - 1) ga0 = M - 1;
  int ga1 = m0 + sra1; if (ga1 > M - 1) ga1 = M - 1;
  const ushort_t* srcA0 = A + (size_t)ga0 * Kdim + ((ca ^ (sra0 & 3)) << 3);
  const ushort_t* srcA1 = A + (size_t)ga1 * Kdim + ((ca ^ (sra1 & 3)) << 3);
  const ushort_t* srcB[4];
  #pragma unroll
  for (int qq = 0; qq < 4; qq++) {
    int srb = qq * 64 + (t >> 2);
    srcB[qq] = Wb + (size_t)(n0 + srb) * Kdim + ((ca ^ (srb & 3)) << 3);
  }

  f32x4 acc[4][8];
  #pragma unroll
  for (int i = 0; i < 4; i++)
    #pragma unroll
    for (int j = 0; j < 8; j++) acc[i][j] = (f32x4){0.f, 0.f, 0.f, 0.f};

  int nk = Kdim >> 5;
  #define STAGE(bufi, koff) { \
    gl_lds16(srcA0 + (koff), &As[bufi][w * 512]); \
    gl_lds16(srcA1 + (koff), &As[bufi][2048 + w * 512]); \
    gl_lds16(srcB[0] + (koff), &Bs[bufi][w * 512]); \
    gl_lds16(srcB[1] + (koff), &Bs[bufi][2048 + w * 512]); \
    gl_lds16(srcB[2] + (koff), &Bs[bufi][4096 + w * 512]); \
    gl_lds16(srcB[3] + (koff), &Bs[bufi][6144 + w * 512]); }

  STAGE(0, 0);
  __syncthreads();
  for (int kt = 0; kt < nk; kt++) {
    int cur = kt & 1;
    if (kt + 1 < nk) STAGE(cur ^ 1, (kt + 1) << 5);
    bf16x8 af[4], bfr[8];
    #pragma unroll
    for (int i = 0; i < 4; i++) {
      int row = wr + i * 16 + fr;
      af[i] = *reinterpret_cast<const bf16x8*>(&As[cur][row * 32 + ((fg ^ (row & 3)) << 3)]);
    }
    #pragma unroll
    for (int j = 0; j < 8; j++) {
      int row = wc + j * 16 + fr;
      bfr[j] = *reinterpret_cast<const bf16x8*>(&Bs[cur][row * 32 + ((fg ^ (row & 3)) << 3)]);
    }
    #pragma unroll
    for (int i = 0; i < 4; i++)
      #pragma unroll
      for (int j = 0; j < 8; j++)
        acc[i][j] = MFMA(af[i], bfr[j], acc[i][j], 0, 0, 0);
    __syncthreads();
  }
  #undef STAGE

  #pragma unroll
  for (int i = 0; i < 4; i++) {
    int mbase = m0 + wr + i * 16 + fg * 4;
    #pragma unroll
    for (int j = 0; j < 8; j++) {
      int n = n0 + wc + j * 16 + fr;
      float bs = bias[n];
      #pragma unroll
      for (int r = 0; r < 4; r++) {
        int m = mbase + r;
        if (m >= M) continue;
        float v = acc[i][j][r] + bs;
        if (RES) v += res[(size_t)m * Ndim + n];
        if (GELU) v = 0.5f * v * (1.f + erff(v * 0.70710678118f));
        if (OMODE == 0) {
          ((float*)out1)[(size_t)m * Ndim + n] = v;
        } else if (OMODE == 1) {
          ((ushort_t*)out1)[(size_t)m * Ndim + n] = f2bfbits(v);
        } else {
          if (n < 512) {
            ((ushort_t*)out1)[(size_t)m * 512 + n] = f2bfbits(v);
          } else {
            int dv = n - 512, hh = dv >> 6, dd = dv & 63;
            int bi = m >> 9, kk = m & (LL - 1);
            out2[(((size_t)(bi * 4 + hh) * 64 + dd) << 9) + kk] = f2bfbits(v);
          }
        }
      }
    }
  }
}

// -------- MFMA flash attention v3 --------
// grid (4 qchunks of 128, H, B); 512 thr / 8 waves, 16 q per wave.
// K and V^T staged per 256-k half via global_load_lds (pre-swizzled src, linear dest).
// Swapped-operand S (q on fr, scalar softmax state), P->PV via shfl, PV gives O^T.
__global__ __launch_bounds__(512) void k_mattn3(const ushort_t* __restrict__ QK,
                                                const ushort_t* __restrict__ VTg,
                                                const int* __restrict__ lens,
                                                ushort_t* __restrict__ O) {
  int b = blockIdx.z, h = blockIdx.y;
  int len = lens[b];
  int q0 = blockIdx.x * 128;
  if (q0 >= len) return;
  int t = threadIdx.x, lane = t & 63, w = t >> 6;
  int fr = lane & 15, fg = lane >> 4;
  __shared__ __align__(16) ushort_t Kh[16384];   // [256 k][64 d], chunk ^= (k&7)
  __shared__ __align__(16) ushort_t Vh[16384];   // [64 d][256 k], chunk ^= (d&7)

  int qw = q0 + w * 16;
  bool qact = qw < len;
  int q = qw + fr;

  const ushort_t* qp = QK + (size_t)(b * LL + q) * 512 + h * 64 + fg * 8;
  bf16x8 qf0 = *reinterpret_cast<const bf16x8*>(qp);
  bf16x8 qf1 = *reinterpret_cast<const bf16x8*>(qp + 32);

  f32x4 ot[4];
  #pragma unroll
  for (int df = 0; df < 4; df++) ot[df] = (f32x4){0.f, 0.f, 0.f, 0.f};
  float m_run = -1e30f, lsum = 0.f;

  for (int kb = 0; kb < len; kb += 256) {
    if (kb) __syncthreads();       // protect prior reads before restage
    // stage K half: LDS[k][c] = Kg[k][c ^ (k&7)]
    #pragma unroll
    for (int rr = 0; rr < 4; rr++) {
      int krow = rr * 64 + w * 8 + (lane >> 3);
      int gk = kb + krow; if (gk > len - 1) gk = len - 1;
      int ch = lane & 7;
      const ushort_t* src = QK + (size_t)(b * LL + gk) * 512 + 256 + h * 64 + ((ch ^ (krow & 7)) << 3);
      gl_lds16(src, &Kh[rr * 4096 + w * 512]);
    }
    // stage V^T half: LDS[d][c] = VTg[d][c ^ (d&7)]
    #pragma unroll
    for (int rr = 0; rr < 4; rr++) {
      int d = rr * 16 + w * 2 + (lane >> 5);
      int ch = lane & 31;
      const ushort_t* src = VTg + (((size_t)(b * 4 + h) * 64 + d) << 9) + kb + ((ch ^ (d & 7)) << 3);
      gl_lds16(src, &Vh[rr * 4096 + w * 512]);
    }
    __syncthreads();

    int lim = min(256, len - kb);
    if (qact) {
      for (int kt = 0; kt < lim; kt += 64) {
        // S^T = K·Q^T
        f32x4 s[4];
        #pragma unroll
        for (int f = 0; f < 4; f++) {
          s[f] = (f32x4){0.f, 0.f, 0.f, 0.f};
          int krow = kt + f * 16 + fr;
          const ushort_t* kp0 = &Kh[krow * 64 + ((fg ^ (krow & 7)) << 3)];
          const ushort_t* kp1 = &Kh[krow * 64 + (((4 + fg) ^ (krow & 7)) << 3)];
          s[f] = MFMA(*reinterpret_cast<const bf16x8*>(kp0), qf0, s[f], 0, 0, 0);
          s[f] = MFMA(*reinterpret_cast<const bf16x8*>(kp1), qf1, s[f], 0, 0, 0);
        }
        int rem = lim - kt;
        #pragma unroll
        for (int f = 0; f < 4; f++)
          #pragma unroll
          for (int r = 0; r < 4; r++)
            s[f][r] = (f * 16 + fg * 4 + r < rem) ? s[f][r] * 0.125f : -1e30f;
        float tm = -1e30f;
        #pragma unroll
        for (int f = 0; f < 4; f++)
          #pragma unroll
          for (int r = 0; r < 4; r++) tm = fmaxf(tm, s[f][r]);
        tm = fmaxf(tm, __shfl_xor(tm, 16, 64));
        tm = fmaxf(tm, __shfl_xor(tm, 32, 64));
        float m_new = fmaxf(m_run, tm);
        float corr = __expf(m_run - m_new);
        float ps = 0.f;
        #pragma unroll
        for (int f = 0; f < 4; f++)
          #pragma unroll
          for (int r = 0; r < 4; r++) {
            float p = __expf(s[f][r] - m_new);
            s[f][r] = p; ps += p;
          }
        ps += __shfl_xor(ps, 16, 64);
        ps += __shfl_xor(ps, 32, 64);
        lsum = lsum * corr + ps;
        m_run = m_new;
        #pragma unroll
        for (int df = 0; df < 4; df++)
          #pragma unroll
          for (int r = 0; r < 4; r++) ot[df][r] *= corr;
        // PV: O^T += Vh · P^T, P B-frag via shfl
        #pragma unroll
        for (int st = 0; st < 2; st++) {
          int fA = st * 2, fB = fA + 1;
          unsigned a0 = pkbf(s[fA][0], s[fA][1]), a1 = pkbf(s[fA][2], s[fA][3]);
          unsigned b0 = pkbf(s[fB][0], s[fB][1]), b1 = pkbf(s[fB][2], s[fB][3]);
          int sA = ((fg & 1) * 2) * 16 + fr;
          int sB = sA + 16;
          unsigned wa0 = __shfl(a0, sA, 64), wb0 = __shfl(b0, sA, 64);
          unsigned wa1 = __shfl(a1, sA, 64), wb1 = __shfl(b1, sA, 64);
          unsigned wa2 = __shfl(a0, sB, 64), wb2 = __shfl(b0, sB, 64);
          unsigned wa3 = __shfl(a1, sB, 64), wb3 = __shfl(b1, sB, 64);
          bool lo = fg < 2;
          U8 pf;
          pf.u[0] = lo ? wa0 : wb0; pf.u[1] = lo ? wa1 : wb1;
          pf.u[2] = lo ? wa2 : wb2; pf.u[3] = lo ? wa3 : wb3;
          int cb = (kt >> 3) + st * 4 + fg;
          #pragma unroll
          for (int df = 0; df < 4; df++) {
            int d = df * 16 + fr;
            const ushort_t* vp = &Vh[d * 256 + ((cb ^ (d & 7)) << 3)];
            ot[df] = MFMA(*reinterpret_cast<const bf16x8*>(vp), pf.v, ot[df], 0, 0, 0);
          }
        }
      }
    }
  }

  if (q < len) {
    float linv = 1.f / lsum;
    #pragma unroll
    for (int df = 0; df < 4; df++) {
      ushort4 ov;
      ov.x = f2bfbits(ot[df][0] * linv);
      ov.y = f2bfbits(ot[df][1] * linv);
      ov.z = f2bfbits(ot[df][2] * linv);
      ov.w = f2bfbits(ot[df][3] * linv);
      *reinterpret_cast<ushort4*>(O + (size_t)(b * LL + q) * DD + h * 64 + df * 16 + fg * 4) = ov;
    }
  }
}

// -------- final attention pooling --------
__global__ __launch_bounds__(256) void k_pool(const float* __restrict__ X,
                                              const int* __restrict__ lens,
                                              bf16* __restrict__ pooled) {
  __shared__ float red[4];
  __shared__ float qs[DD];
  __shared__ float sc[LL];
  int b = blockIdx.x, t = threadIdx.x;
  int len = lens[b];
  const float* Xb = X + (size_t)b * LL * DD;
  qs[t] = Xb[(size_t)(len - 1) * DD + t];
  __syncthreads();
  for (int l = t; l < LL; l += 256) {
    float s = -1e30f;
    if (l < len) {
      const float4* xr = reinterpret_cast<const float4*>(Xb + (size_t)l * DD);
      const float4* qq = reinterpret_cast<const float4*>(qs);
      float a0 = 0, a1 = 0, a2 = 0, a3 = 0;
      for (int k4 = 0; k4 < 64; k4++) {
        float4 xv = xr[k4], qv = qq[k4];
        a0 += xv.x * qv.x; a1 += xv.y * qv.y; a2 += xv.z * qv.z; a3 += xv.w * qv.w;
      }
      s = (a0 + a1) + (a2 + a3);
    }
    sc[l] = s;
  }
  __syncthreads();
  float mx = fmaxf(sc[t], sc[t + 256]);
  #pragma unroll
  for (int off = 32; off > 0; off >>= 1) mx = fmaxf(mx, __shfl_down(mx, off, 64));
  __syncthreads();
  if ((t & 63) == 0) red[t >> 6] = mx;
  __syncthreads();
  mx = fmaxf(fmaxf(red[0], red[1]), fmaxf(red[2], red[3]));
  float e0 = (t < len) ? __expf(sc[t] - mx) : 0.f;
  float e1 = (t + 256 < len) ? __expf(sc[t + 256] - mx) : 0.f;
  float ssum = blk_sum(e0 + e1, red);
  float inv = 1.f / ssum;
  __syncthreads();
  sc[t] = e0 * inv; sc[t + 256] = e1 * inv;
  __syncthreads();
  float acc = 0.f;
  for (int l = 0; l < len; l++) acc += sc[l] * Xb[(size_t)l * DD + t];
  pooled[b * DD + t] = __float2bfloat16(acc);
}

extern "C" void kernel_launch(void* const* d_in, const int* in_sizes, int n_in,
                              void* d_out, int out_size, void* d_ws, size_t ws_size,
                              hipStream_t stream) {
  const int*   tokens  = (const int*)d_in[0];
  const float* tok_emb = (const float*)d_in[2];
  const float* pos_emb = (const float*)d_in[3];
  const float* emb_g   = (const float*)d_in[4];
  const float* emb_b   = (const float*)d_in[5];
  const float* ln1_g   = (const float*)d_in[6];
  const float* ln1_b   = (const float*)d_in[7];
  const float* Wqkv    = (const float*)d_in[8];
  const float* bqkv    = (const float*)d_in[9];
  const float* Wo      = (const float*)d_in[10];
  const float* bo      = (const float*)d_in[11];
  const float* ln2_g   = (const float*)d_in[12];
  const float* ln2_b   = (const float*)d_in[13];
  const float* W1      = (const float*)d_in[14];
  const float* b1      = (const float*)d_in[15];
  const float* W2      = (const float*)d_in[16];
  const float* b2      = (const float*)d_in[17];
  const float* cls_W   = (const float*)d_in[22];
  const float* cls_b   = (const float*)d_in[23];

  char* ws = (char*)d_ws;
  float*    X    = (float*)ws;                         // 33,554,432 B
  ushort_t* QKb  = (ushort_t*)(ws + 33554432);         // 33,554,432 B: [m][512] Q|K; also FF1 out; also cls_W bf16
  ushort_t* VTg  = (ushort_t*)(ws + 67108864);         // 16,777,216 B: [b*4+h][64][512]
  ushort_t* Hb   = (ushort_t*)(ws + 83886080);         // 16,777,216 B
  ushort_t* WB   = (ushort_t*)(ws + 100663296);        //  1,048,576 B per-layer weights bf16
  ushort_t* POOL = (ushort_t*)(ws + 101711872);        //     32,768 B
  int*      LEN  = (int*)(ws + 101744640);             //        256 B

  const int OFF_QKV = 0, OFF_WO = 196608, OFF_W1 = 262144, OFF_W2 = 393216;

  k_lens<<<BB, 256, 0, stream>>>(tokens, LEN);
  k_embed4<<<MM / 4, 256, 0, stream>>>(tokens, tok_emb, pos_emb, emb_g, emb_b, X);

  for (int e = 0; e < KK; e++) {
    k_cvtw<<<512, 256, 0, stream>>>(Wqkv + (size_t)e * 196608, Wo + (size_t)e * 65536,
                                    W1 + (size_t)e * 131072, W2 + (size_t)e * 131072, WB);
    k_ln4<<<MM / 4, 256, 0, stream>>>(X, ln1_g + e * DD, ln1_b + e * DD, LEN, (bf16*)Hb);
    // QKV projection -> QK[m][512] + VT[b][h][d][k]
    k_mgemm<2, false, false><<<dim3(3, 256), 256, 0, stream>>>(
        Hb, WB + OFF_QKV, bqkv + e * 3 * DD, nullptr, QKb, VTg, LEN, MM, 3 * DD, DD);
    k_mattn3<<<dim3(4, HH, BB), 512, 0, stream>>>(QKb, VTg, LEN, Hb);
    k_mgemm<0, false, true><<<dim3(1, 256), 256, 0, stream>>>(
        Hb, WB + OFF_WO, bo + e * DD, X, X, nullptr, LEN, MM, DD, DD);
    k_ln4<<<MM / 4, 256, 0, stream>>>(X, ln2_g + e * DD, ln2_b + e * DD, LEN, (bf16*)Hb);
    k_mgemm<1, true, false><<<dim3(2, 256), 256, 0, stream>>>(
        Hb, WB + OFF_W1, b1 + e * FF, nullptr, QKb, nullptr, LEN, MM, FF, DD);
    k_mgemm<0, false, true><<<dim3(1, 256), 256, 0, stream>>>(
        QKb, WB + OFF_W2, b2 + e * DD, X, X, nullptr, LEN, MM, DD, FF);
  }

  k_pool<<<BB, 256, 0, stream>>>(X, LEN, (bf16*)POOL);
  k_cvt<<<8000, 256, 0, stream>>>(cls_W, QKb, VV * DD);
  k_mgemm<0, false, false><<<dim3(125, 1), 256, 0, stream>>>(
      POOL, QKb, cls_b, nullptr, (float*)d_out, nullptr, LEN, BB, VV, DD);
}

// Round 7
// 1088.658 us; speedup vs baseline: 1.3850x; 1.3850x over previous
//
#include <hip/hip_runtime.h>
#include <hip/hip_bf16.h>

#define BB 64
#define LL 512
#define DD 256
#define VV 32000
#define KK 6
#define HH 4
#define FF 512
#define MM (BB * LL)

typedef __hip_bfloat16 bf16;
typedef unsigned short ushort_t;
typedef __attribute__((ext_vector_type(8))) __bf16 bf16x8;
typedef __attribute__((ext_vector_type(4))) float f32x4;
#define MFMA __builtin_amdgcn_mfma_f32_16x16x32_bf16

__device__ __forceinline__ ushort_t f2bfbits(float x) {
  return __builtin_bit_cast(unsigned short, (__bf16)x);
}
__device__ __forceinline__ unsigned pkbf(float lo, float hi) {
  return (unsigned)f2bfbits(lo) | ((unsigned)f2bfbits(hi) << 16);
}
union U8 { unsigned u[4]; bf16x8 v; };

// async global->LDS, 16B/lane; dest must be WAVE-UNIFORM base (HW adds lane*16)
__device__ __forceinline__ void gl_lds16(const ushort_t* g, ushort_t* l) {
  __builtin_amdgcn_global_load_lds(
      (const __attribute__((address_space(1))) unsigned int*)g,
      (__attribute__((address_space(3))) unsigned int*)l, 16, 0, 0);
}

__device__ __forceinline__ float blk_sum(float v, float* red) {
  #pragma unroll
  for (int o = 32; o > 0; o >>= 1) v += __shfl_down(v, o, 64);
  __syncthreads();
  if ((threadIdx.x & 63) == 0) red[threadIdx.x >> 6] = v;
  __syncthreads();
  return red[0] + red[1] + red[2] + red[3];
}

__global__ __launch_bounds__(256) void k_lens(const int* __restrict__ tokens, int* __restrict__ lens) {
  __shared__ float red[4];
  int b = blockIdx.x, t = threadIdx.x;
  float c = (tokens[b * LL + t] != 0 ? 1.f : 0.f) + (tokens[b * LL + 256 + t] != 0 ? 1.f : 0.f);
  float s = blk_sum(c, red);
  if (t == 0) lens[b] = (int)(s + 0.5f);
}

__global__ __launch_bounds__(256) void k_embed4(const int* __restrict__ tokens,
                                                const float* __restrict__ tok_emb,
                                                const float* __restrict__ pos_emb,
                                                const float* __restrict__ g,
                                                const float* __restrict__ be,
                                                float* __restrict__ X) {
  int wid = threadIdx.x >> 6, lane = threadIdx.x & 63;
  int row = blockIdx.x * 4 + wid;
  int l = row & (LL - 1);
  int tok = tokens[row];
  float4 a = *reinterpret_cast<const float4*>(tok_emb + (size_t)tok * DD + lane * 4);
  float4 p = *reinterpret_cast<const float4*>(pos_emb + (size_t)l * DD + lane * 4);
  float4 v = {a.x + p.x, a.y + p.y, a.z + p.z, a.w + p.w};
  float s = v.x + v.y + v.z + v.w;
  float q = v.x * v.x + v.y * v.y + v.z * v.z + v.w * v.w;
  #pragma unroll
  for (int o = 32; o > 0; o >>= 1) { s += __shfl_xor(s, o, 64); q += __shfl_xor(q, o, 64); }
  float mu = s * (1.f / DD);
  float rstd = rsqrtf(q * (1.f / DD) - mu * mu + 1e-5f);
  float4 gv = *reinterpret_cast<const float4*>(g + lane * 4);
  float4 bv = *reinterpret_cast<const float4*>(be + lane * 4);
  float4 o4 = {(v.x - mu) * rstd * gv.x + bv.x, (v.y - mu) * rstd * gv.y + bv.y,
               (v.z - mu) * rstd * gv.z + bv.z, (v.w - mu) * rstd * gv.w + bv.w};
  *reinterpret_cast<float4*>(X + (size_t)row * DD + lane * 4) = o4;
}

__global__ __launch_bounds__(256) void k_ln4(const float* __restrict__ X,
                                             const float* __restrict__ g,
                                             const float* __restrict__ be,
                                             const int* __restrict__ lens,
                                             bf16* __restrict__ H) {
  int wid = threadIdx.x >> 6, lane = threadIdx.x & 63;
  int row = blockIdx.x * 4 + wid;
  int b = row >> 9, l = row & (LL - 1);
  if (l >= lens[b]) return;
  float4 v = *reinterpret_cast<const float4*>(X + (size_t)row * DD + lane * 4);
  float s = v.x + v.y + v.z + v.w;
  float q = v.x * v.x + v.y * v.y + v.z * v.z + v.w * v.w;
  #pragma unroll
  for (int o = 32; o > 0; o >>= 1) { s += __shfl_xor(s, o, 64); q += __shfl_xor(q, o, 64); }
  float mu = s * (1.f / DD);
  float rstd = rsqrtf(q * (1.f / DD) - mu * mu + 1e-5f);
  float4 gv = *reinterpret_cast<const float4*>(g + lane * 4);
  float4 bv = *reinterpret_cast<const float4*>(be + lane * 4);
  ushort4 o4;
  o4.x = f2bfbits((v.x - mu) * rstd * gv.x + bv.x);
  o4.y = f2bfbits((v.y - mu) * rstd * gv.y + bv.y);
  o4.z = f2bfbits((v.z - mu) * rstd * gv.z + bv.z);
  o4.w = f2bfbits((v.w - mu) * rstd * gv.w + bv.w);
  *reinterpret_cast<ushort4*>((ushort_t*)H + (size_t)row * DD + lane * 4) = o4;
}

__global__ __launch_bounds__(256) void k_cvtw(const float* __restrict__ w0, const float* __restrict__ w1,
                                              const float* __restrict__ w2, const float* __restrict__ w3,
                                              ushort_t* __restrict__ d) {
  int i = (blockIdx.x * 256 + threadIdx.x) * 4;
  const float* s; int off;
  if (i < 196608)      { s = w0; off = i; }
  else if (i < 262144) { s = w1; off = i - 196608; }
  else if (i < 393216) { s = w2; off = i - 262144; }
  else                 { s = w3; off = i - 393216; }
  float4 v = *reinterpret_cast<const float4*>(s + off);
  ushort4 o;
  o.x = f2bfbits(v.x); o.y = f2bfbits(v.y); o.z = f2bfbits(v.z); o.w = f2bfbits(v.w);
  *reinterpret_cast<ushort4*>(d + i) = o;
}

// -------- MFMA GEMM: MT x 128 tile, BK=32, 4 waves, dbuf, conflict-free LDS --------
// LDS layout: L[row][c] = G[row][c ^ ((row>>1)&3)] (16B chunks). Per-16-lane-quarter
// read slot = 4*(row&1) + (fg ^ ((row>>1)&3)) -> all 8 slots 2-way = free.
template <int MT, bool GELU, bool RES, bool OUTBF16>
__global__ __launch_bounds__(256) void k_mgemm(const ushort_t* __restrict__ A,
                                               const ushort_t* __restrict__ Wb,
                                               const float* __restrict__ bias,
                                               const float* __restrict__ res,
                                               void* __restrict__ outp,
                                               const int* __restrict__ lens,
                                               int M, int Ndim, int Kdim) {
  constexpr int JF = (MT == 128) ? 4 : 2;
  int n0 = blockIdx.x * 128, m0 = blockIdx.y * MT;
  if (M > 128) {
    if ((m0 & (LL - 1)) >= lens[m0 >> 9]) return;   // uniform: whole tile is padding
  }
  __shared__ __align__(16) ushort_t As[2][MT * 32];
  __shared__ __align__(16) ushort_t Bs[2][4096];
  int t = threadIdx.x, lane = t & 63, w = t >> 6;
  int wr = (MT == 128) ? (w >> 1) * 64 : 0;
  int wc = (MT == 128) ? (w & 1) * 64 : w * 32;
  int fr = lane & 15, fg = lane >> 4;

  // staging sources: dest linear, source chunk pre-swizzled by LOCAL row
  int cA = lane & 3;
  int rA0 = (MT == 128 ? w * 32 : w * 16) + (lane >> 2);
  const ushort_t* gA0 = A + (size_t)min(m0 + rA0, M - 1) * Kdim + ((cA ^ ((rA0 >> 1) & 3)) << 3);
  const ushort_t* gA1 = nullptr;
  if constexpr (MT == 128) {
    int rA1 = rA0 + 16;
    gA1 = A + (size_t)min(m0 + rA1, M - 1) * Kdim + ((cA ^ ((rA1 >> 1) & 3)) << 3);
  }
  int rB0 = w * 32 + (lane >> 2), rB1 = rB0 + 16;
  const ushort_t* gB0 = Wb + (size_t)(n0 + rB0) * Kdim + ((cA ^ ((rB0 >> 1) & 3)) << 3);
  const ushort_t* gB1 = Wb + (size_t)(n0 + rB1) * Kdim + ((cA ^ ((rB1 >> 1) & 3)) << 3);
  int aoff = (MT == 128) ? w * 1024 : w * 512;
  int boff = w * 1024;

  f32x4 acc[4][JF];
  #pragma unroll
  for (int i = 0; i < 4; i++)
    #pragma unroll
    for (int j = 0; j < JF; j++) acc[i][j] = (f32x4){0.f, 0.f, 0.f, 0.f};

  int nk = Kdim >> 5;
  #define STAGE(bi, koff) { \
    gl_lds16(gA0 + (koff), &As[bi][aoff]); \
    if constexpr (MT == 128) gl_lds16(gA1 + (koff), &As[bi][aoff + 512]); \
    gl_lds16(gB0 + (koff), &Bs[bi][boff]); \
    gl_lds16(gB1 + (koff), &Bs[bi][boff + 512]); }

  STAGE(0, 0);
  __syncthreads();
  for (int kt = 0; kt < nk; kt++) {
    int cur = kt & 1;
    if (kt + 1 < nk) STAGE(cur ^ 1, (kt + 1) << 5);
    bf16x8 af[4], bfr[JF];
    #pragma unroll
    for (int i = 0; i < 4; i++) {
      int row = wr + i * 16 + fr;
      af[i] = *reinterpret_cast<const bf16x8*>(&As[cur][row * 32 + ((fg ^ ((row >> 1) & 3)) << 3)]);
    }
    #pragma unroll
    for (int j = 0; j < JF; j++) {
      int row = wc + j * 16 + fr;
      bfr[j] = *reinterpret_cast<const bf16x8*>(&Bs[cur][row * 32 + ((fg ^ ((row >> 1) & 3)) << 3)]);
    }
    #pragma unroll
    for (int i = 0; i < 4; i++)
      #pragma unroll
      for (int j = 0; j < JF; j++)
        acc[i][j] = MFMA(af[i], bfr[j], acc[i][j], 0, 0, 0);
    __syncthreads();
  }
  #undef STAGE

  #pragma unroll
  for (int i = 0; i < 4; i++) {
    int mbase = m0 + wr + i * 16 + fg * 4;
    #pragma unroll
    for (int j = 0; j < JF; j++) {
      int n = n0 + wc + j * 16 + fr;
      float bs = bias[n];
      #pragma unroll
      for (int r = 0; r < 4; r++) {
        int m = mbase + r;
        if (m >= M) continue;
        float v = acc[i][j][r] + bs;
        if (RES) v += res[(size_t)m * Ndim + n];
        if (GELU) v = 0.5f * v * (1.f + erff(v * 0.70710678118f));
        if (OUTBF16) ((ushort_t*)outp)[(size_t)m * Ndim + n] = f2bfbits(v);
        else         ((float*)outp)[(size_t)m * Ndim + n] = v;
      }
    }
  }
}

// -------- MFMA flash attention v5 (fixed V read swizzle) --------
// grid (4 qchunks of 128, H, B); 512 thr / 8 waves, 16 q per wave; QKV [m][768].
// K [256][64] per-half via gl_lds (src pre-swizzled by (krow&7)); V^T [64][256]
// per-half via scalar transpose with S(d) = (d ^ (d>>3)) & 7 chunk swizzle;
// read side must mask S(d) to 3 bits BEFORE XOR with the k-chunk (bug fix).
__global__ __launch_bounds__(512) void k_mattn5(const ushort_t* __restrict__ QKV,
                                                const int* __restrict__ lens,
                                                ushort_t* __restrict__ O) {
  int b = blockIdx.z, h = blockIdx.y;
  int len = lens[b];
  int q0 = blockIdx.x * 128;
  if (q0 >= len) return;
  int t = threadIdx.x, lane = t & 63, w = t >> 6;
  int fr = lane & 15, fg = lane >> 4;
  __shared__ __align__(16) ushort_t Kh[16384];   // [256 k][64 d], chunk ^= (k&7)
  __shared__ __align__(16) ushort_t Vh[16384];   // [64 d][256 k], chunk ^= S(d)

  const ushort_t* base = QKV + (size_t)b * LL * 768;
  int qw = q0 + w * 16;
  bool qact = qw < len;
  int q = qw + fr;

  const ushort_t* qp = base + (size_t)q * 768 + h * 64 + fg * 8;
  bf16x8 qf0 = *reinterpret_cast<const bf16x8*>(qp);
  bf16x8 qf1 = *reinterpret_cast<const bf16x8*>(qp + 32);

  f32x4 ot[4];
  #pragma unroll
  for (int df = 0; df < 4; df++) ot[df] = (f32x4){0.f, 0.f, 0.f, 0.f};
  float m_run = -1e30f, lsum = 0.f;

  for (int kb = 0; kb < len; kb += 256) {
    if (kb) __syncthreads();       // protect prior reads before restage
    int lim = min(256, len - kb);
    // stage K half: LDS[k][c] = Kg[k][c ^ (k&7)]
    #pragma unroll
    for (int rr = 0; rr < 4; rr++) {
      if (rr * 64 >= lim) break;   // uniform
      int krow = rr * 64 + w * 8 + (lane >> 3);
      int gk = kb + krow; if (gk > len - 1) gk = len - 1;
      int ch = lane & 7;
      const ushort_t* src = base + (size_t)gk * 768 + 256 + h * 64 + ((ch ^ (krow & 7)) << 3);
      gl_lds16(src, &Kh[rr * 4096 + w * 512]);
    }
    // stage V^T half: coalesced 16B reads, scalar swizzled stores (clamped rows
    // are finite; p=0 masks them in PV)
    #pragma unroll
    for (int it = 0; it < 4; it++) {
      int c = it * 512 + t;
      int k = c >> 3, dg = c & 7;
      int gk = kb + k; if (gk > len - 1) gk = len - 1;
      uint4 vv = *reinterpret_cast<const uint4*>(base + (size_t)gk * 768 + 512 + h * 64 + dg * 8);
      unsigned uu[4] = {vv.x, vv.y, vv.z, vv.w};
      #pragma unroll
      for (int j = 0; j < 4; j++) {
        int d0 = dg * 8 + j * 2, d1 = d0 + 1;
        int s0 = (d0 ^ (d0 >> 3)) & 7, s1 = (d1 ^ (d1 >> 3)) & 7;
        Vh[d0 * 256 + (((k >> 3) ^ s0) << 3) + (k & 7)] = (ushort_t)(uu[j] & 0xffff);
        Vh[d1 * 256 + (((k >> 3) ^ s1) << 3) + (k & 7)] = (ushort_t)(uu[j] >> 16);
      }
    }
    __syncthreads();

    if (qact) {
      for (int kt = 0; kt < lim; kt += 64) {
        // S^T = K·Q^T : k on (fg,r), q on fr
        f32x4 s[4];
        #pragma unroll
        for (int f = 0; f < 4; f++) {
          s[f] = (f32x4){0.f, 0.f, 0.f, 0.f};
          int krow = kt + f * 16 + fr;
          const ushort_t* kp0 = &Kh[krow * 64 + ((fg ^ (krow & 7)) << 3)];
          const ushort_t* kp1 = &Kh[krow * 64 + (((4 + fg) ^ (krow & 7)) << 3)];
          s[f] = MFMA(*reinterpret_cast<const bf16x8*>(kp0), qf0, s[f], 0, 0, 0);
          s[f] = MFMA(*reinterpret_cast<const bf16x8*>(kp1), qf1, s[f], 0, 0, 0);
        }
        int rem = lim - kt;
        #pragma unroll
        for (int f = 0; f < 4; f++)
          #pragma unroll
          for (int r = 0; r < 4; r++)
            s[f][r] = (f * 16 + fg * 4 + r < rem) ? s[f][r] * 0.125f : -1e30f;
        float tm = -1e30f;
        #pragma unroll
        for (int f = 0; f < 4; f++)
          #pragma unroll
          for (int r = 0; r < 4; r++) tm = fmaxf(tm, s[f][r]);
        tm = fmaxf(tm, __shfl_xor(tm, 16, 64));
        tm = fmaxf(tm, __shfl_xor(tm, 32, 64));
        float m_new = fmaxf(m_run, tm);
        float corr = __expf(m_run - m_new);
        float ps = 0.f;
        #pragma unroll
        for (int f = 0; f < 4; f++)
          #pragma unroll
          for (int r = 0; r < 4; r++) {
            float p = __expf(s[f][r] - m_new);
            s[f][r] = p; ps += p;
          }
        ps += __shfl_xor(ps, 16, 64);
        ps += __shfl_xor(ps, 32, 64);
        lsum = lsum * corr + ps;
        m_run = m_new;
        #pragma unroll
        for (int df = 0; df < 4; df++)
          #pragma unroll
          for (int r = 0; r < 4; r++) ot[df][r] *= corr;
        // PV: O^T += Vh · P^T, P B-frag via shfl
        #pragma unroll
        for (int st = 0; st < 2; st++) {
          int fA = st * 2, fB = fA + 1;
          unsigned a0 = pkbf(s[fA][0], s[fA][1]), a1 = pkbf(s[fA][2], s[fA][3]);
          unsigned b0 = pkbf(s[fB][0], s[fB][1]), b1 = pkbf(s[fB][2], s[fB][3]);
          int sA = ((fg & 1) * 2) * 16 + fr;
          int sB = sA + 16;
          unsigned wa0 = __shfl(a0, sA, 64), wb0 = __shfl(b0, sA, 64);
          unsigned wa1 = __shfl(a1, sA, 64), wb1 = __shfl(b1, sA, 64);
          unsigned wa2 = __shfl(a0, sB, 64), wb2 = __shfl(b0, sB, 64);
          unsigned wa3 = __shfl(a1, sB, 64), wb3 = __shfl(b1, sB, 64);
          bool lo = fg < 2;
          U8 pf;
          pf.u[0] = lo ? wa0 : wb0; pf.u[1] = lo ? wa1 : wb1;
          pf.u[2] = lo ? wa2 : wb2; pf.u[3] = lo ? wa3 : wb3;
          int cb = (kt >> 3) + st * 4 + fg;
          #pragma unroll
          for (int df = 0; df < 4; df++) {
            int d = df * 16 + fr;
            int sd = (d ^ (d >> 3)) & 7;                         // FIX: mask before XOR
            const ushort_t* vp = &Vh[d * 256 + ((cb ^ sd) << 3)];
            ot[df] = MFMA(*reinterpret_cast<const bf16x8*>(vp), pf.v, ot[df], 0, 0, 0);
          }
        }
      }
    }
  }

  if (q < len) {
    float linv = 1.f / lsum;
    #pragma unroll
    for (int df = 0; df < 4; df++) {
      ushort4 ov;
      ov.x = f2bfbits(ot[df][0] * linv);
      ov.y = f2bfbits(ot[df][1] * linv);
      ov.z = f2bfbits(ot[df][2] * linv);
      ov.w = f2bfbits(ot[df][3] * linv);
      *reinterpret_cast<ushort4*>(O + (size_t)(b * LL + q) * DD + h * 64 + df * 16 + fg * 4) = ov;
    }
  }
}

// -------- final attention pooling --------
__global__ __launch_bounds__(256) void k_pool(const float* __restrict__ X,
                                              const int* __restrict__ lens,
                                              bf16* __restrict__ pooled) {
  __shared__ float red[4];
  __shared__ float qs[DD];
  __shared__ float sc[LL];
  int b = blockIdx.x, t = threadIdx.x;
  int len = lens[b];
  const float* Xb = X + (size_t)b * LL * DD;
  qs[t] = Xb[(size_t)(len - 1) * DD + t];
  __syncthreads();
  for (int l = t; l < LL; l += 256) {
    float s = -1e30f;
    if (l < len) {
      const float4* xr = reinterpret_cast<const float4*>(Xb + (size_t)l * DD);
      const float4* qq = reinterpret_cast<const float4*>(qs);
      float a0 = 0, a1 = 0, a2 = 0, a3 = 0;
      for (int k4 = 0; k4 < 64; k4++) {
        float4 xv = xr[k4], qv = qq[k4];
        a0 += xv.x * qv.x; a1 += xv.y * qv.y; a2 += xv.z * qv.z; a3 += xv.w * qv.w;
      }
      s = (a0 + a1) + (a2 + a3);
    }
    sc[l] = s;
  }
  __syncthreads();
  float mx = fmaxf(sc[t], sc[t + 256]);
  #pragma unroll
  for (int off = 32; off > 0; off >>= 1) mx = fmaxf(mx, __shfl_down(mx, off, 64));
  __syncthreads();
  if ((t & 63) == 0) red[t >> 6] = mx;
  __syncthreads();
  mx = fmaxf(fmaxf(red[0], red[1]), fmaxf(red[2], red[3]));
  float e0 = (t < len) ? __expf(sc[t] - mx) : 0.f;
  float e1 = (t + 256 < len) ? __expf(sc[t + 256] - mx) : 0.f;
  float ssum = blk_sum(e0 + e1, red);
  float inv = 1.f / ssum;
  __syncthreads();
  sc[t] = e0 * inv; sc[t + 256] = e1 * inv;
  __syncthreads();
  float acc = 0.f;
  for (int l = 0; l < len; l++) acc += sc[l] * Xb[(size_t)l * DD + t];
  pooled[b * DD + t] = __float2bfloat16(acc);
}

// -------- classifier: logits[64,32000] = POOL(bf16) @ cls_W(f32->bf16 in reg)^T + b --------
__global__ __launch_bounds__(512) void k_cls(const ushort_t* __restrict__ POOL,
                                             const float* __restrict__ W,
                                             const float* __restrict__ bias,
                                             float* __restrict__ out) {
  int t = threadIdx.x, lane = t & 63, w = t >> 6;
  int fr = lane & 15, fg = lane >> 4;
  int n = blockIdx.x * 128 + w * 16 + fr;
  const float* wp = W + (size_t)n * DD + fg * 8;
  f32x4 acc[4];
  #pragma unroll
  for (int i = 0; i < 4; i++) acc[i] = (f32x4){0.f, 0.f, 0.f, 0.f};
  for (int k0 = 0; k0 < DD; k0 += 32) {
    float4 f0 = *reinterpret_cast<const float4*>(wp + k0);
    float4 f1 = *reinterpret_cast<const float4*>(wp + k0 + 4);
    U8 bfr;
    bfr.u[0] = pkbf(f0.x, f0.y); bfr.u[1] = pkbf(f0.z, f0.w);
    bfr.u[2] = pkbf(f1.x, f1.y); bfr.u[3] = pkbf(f1.z, f1.w);
    #pragma unroll
    for (int i = 0; i < 4; i++) {
      bf16x8 af = *reinterpret_cast<const bf16x8*>(POOL + (size_t)(i * 16 + fr) * DD + k0 + fg * 8);
      acc[i] = MFMA(af, bfr.v, acc[i], 0, 0, 0);
    }
  }
  float bs = bias[n];
  #pragma unroll
  for (int i = 0; i < 4; i++)
    #pragma unroll
    for (int r = 0; r < 4; r++)
      out[(size_t)(i * 16 + fg * 4 + r) * VV + n] = acc[i][r] + bs;
}

extern "C" void kernel_launch(void* const* d_in, const int* in_sizes, int n_in,
                              void* d_out, int out_size, void* d_ws, size_t ws_size,
                              hipStream_t stream) {
  const int*   tokens  = (const int*)d_in[0];
  const float* tok_emb = (const float*)d_in[2];
  const float* pos_emb = (const float*)d_in[3];
  const float* emb_g   = (const float*)d_in[4];
  const float* emb_b   = (const float*)d_in[5];
  const float* ln1_g   = (const float*)d_in[6];
  const float* ln1_b   = (const float*)d_in[7];
  const float* Wqkv    = (const float*)d_in[8];
  const float* bqkv    = (const float*)d_in[9];
  const float* Wo      = (const float*)d_in[10];
  const float* bo      = (const float*)d_in[11];
  const float* ln2_g   = (const float*)d_in[12];
  const float* ln2_b   = (const float*)d_in[13];
  const float* W1      = (const float*)d_in[14];
  const float* b1      = (const float*)d_in[15];
  const float* W2      = (const float*)d_in[16];
  const float* b2      = (const float*)d_in[17];
  const float* cls_W   = (const float*)d_in[22];
  const float* cls_b   = (const float*)d_in[23];

  char* ws = (char*)d_ws;
  float*    X    = (float*)ws;                         // 33,554,432 B
  ushort_t* QKV  = (ushort_t*)(ws + 33554432);         // 50,331,648 B (QKV [m][768] / FF1 [m][512])
  ushort_t* Hb   = (ushort_t*)(ws + 83886080);         // 16,777,216 B
  ushort_t* WB   = (ushort_t*)(ws + 100663296);        //  1,048,576 B per-layer weights bf16
  ushort_t* POOL = (ushort_t*)(ws + 101711872);        //     32,768 B
  int*      LEN  = (int*)(ws + 101744640);             //        256 B

  const int OFF_QKV = 0, OFF_WO = 196608, OFF_W1 = 262144, OFF_W2 = 393216;

  k_lens<<<BB, 256, 0, stream>>>(tokens, LEN);
  k_embed4<<<MM / 4, 256, 0, stream>>>(tokens, tok_emb, pos_emb, emb_g, emb_b, X);

  for (int e = 0; e < KK; e++) {
    k_cvtw<<<512, 256, 0, stream>>>(Wqkv + (size_t)e * 196608, Wo + (size_t)e * 65536,
                                    W1 + (size_t)e * 131072, W2 + (size_t)e * 131072, WB);
    k_ln4<<<MM / 4, 256, 0, stream>>>(X, ln1_g + e * DD, ln1_b + e * DD, LEN, (bf16*)Hb);
    k_mgemm<128, false, false, true><<<dim3(6, 256), 256, 0, stream>>>(
        Hb, WB + OFF_QKV, bqkv + e * 3 * DD, nullptr, QKV, LEN, MM, 3 * DD, DD);
    k_mattn5<<<dim3(4, HH, BB), 512, 0, stream>>>(QKV, LEN, Hb);
    k_mgemm<64, false, true, false><<<dim3(2, 512), 256, 0, stream>>>(
        Hb, WB + OFF_WO, bo + e * DD, X, X, LEN, MM, DD, DD);
    k_ln4<<<MM / 4, 256, 0, stream>>>(X, ln2_g + e * DD, ln2_b + e * DD, LEN, (bf16*)Hb);
    k_mgemm<128, true, false, true><<<dim3(4, 256), 256, 0, stream>>>(
        Hb, WB + OFF_W1, b1 + e * FF, nullptr, QKV, LEN, MM, FF, DD);
    k_mgemm<64, false, true, false><<<dim3(2, 512), 256, 0, stream>>>(
        QKV, WB + OFF_W2, b2 + e * DD, X, X, LEN, MM, DD, FF);
  }

  k_pool<<<BB, 256, 0, stream>>>(X, LEN, (bf16*)POOL);
  k_cls<<<dim3(VV / 128), 512, 0, stream>>>(POOL, cls_W, cls_b, (float*)d_out);
}

// Round 8
// 1071.244 us; speedup vs baseline: 1.4075x; 1.0163x over previous
//
#include <hip/hip_runtime.h>
#include <hip/hip_bf16.h>

#define BB 64
#define LL 512
#define DD 256
#define VV 32000
#define KK 6
#define HH 4
#define FF 512
#define MM (BB * LL)

typedef __hip_bfloat16 bf16;
typedef unsigned short ushort_t;
typedef __attribute__((ext_vector_type(8))) __bf16 bf16x8;
typedef __attribute__((ext_vector_type(4))) float f32x4;
#define MFMA __builtin_amdgcn_mfma_f32_16x16x32_bf16

__device__ __forceinline__ ushort_t f2bfbits(float x) {
  return __builtin_bit_cast(unsigned short, (__bf16)x);
}
__device__ __forceinline__ unsigned pkbf(float lo, float hi) {
  return (unsigned)f2bfbits(lo) | ((unsigned)f2bfbits(hi) << 16);
}
union U8 { unsigned u[4]; bf16x8 v; };

// async global->LDS, 16B/lane; dest must be WAVE-UNIFORM base (HW adds lane*16)
__device__ __forceinline__ void gl_lds16(const ushort_t* g, ushort_t* l) {
  __builtin_amdgcn_global_load_lds(
      (const __attribute__((address_space(1))) unsigned int*)g,
      (__attribute__((address_space(3))) unsigned int*)l, 16, 0, 0);
}

__device__ __forceinline__ float blk_sum(float v, float* red) {
  #pragma unroll
  for (int o = 32; o > 0; o >>= 1) v += __shfl_down(v, o, 64);
  __syncthreads();
  if ((threadIdx.x & 63) == 0) red[threadIdx.x >> 6] = v;
  __syncthreads();
  return red[0] + red[1] + red[2] + red[3];
}

__global__ __launch_bounds__(256) void k_lens(const int* __restrict__ tokens, int* __restrict__ lens) {
  __shared__ float red[4];
  int b = blockIdx.x, t = threadIdx.x;
  float c = (tokens[b * LL + t] != 0 ? 1.f : 0.f) + (tokens[b * LL + 256 + t] != 0 ? 1.f : 0.f);
  float s = blk_sum(c, red);
  if (t == 0) lens[b] = (int)(s + 0.5f);
}

__global__ __launch_bounds__(256) void k_embed4(const int* __restrict__ tokens,
                                                const float* __restrict__ tok_emb,
                                                const float* __restrict__ pos_emb,
                                                const float* __restrict__ g,
                                                const float* __restrict__ be,
                                                float* __restrict__ X) {
  int wid = threadIdx.x >> 6, lane = threadIdx.x & 63;
  int row = blockIdx.x * 4 + wid;
  int l = row & (LL - 1);
  int tok = tokens[row];
  float4 a = *reinterpret_cast<const float4*>(tok_emb + (size_t)tok * DD + lane * 4);
  float4 p = *reinterpret_cast<const float4*>(pos_emb + (size_t)l * DD + lane * 4);
  float4 v = {a.x + p.x, a.y + p.y, a.z + p.z, a.w + p.w};
  float s = v.x + v.y + v.z + v.w;
  float q = v.x * v.x + v.y * v.y + v.z * v.z + v.w * v.w;
  #pragma unroll
  for (int o = 32; o > 0; o >>= 1) { s += __shfl_xor(s, o, 64); q += __shfl_xor(q, o, 64); }
  float mu = s * (1.f / DD);
  float rstd = rsqrtf(q * (1.f / DD) - mu * mu + 1e-5f);
  float4 gv = *reinterpret_cast<const float4*>(g + lane * 4);
  float4 bv = *reinterpret_cast<const float4*>(be + lane * 4);
  float4 o4 = {(v.x - mu) * rstd * gv.x + bv.x, (v.y - mu) * rstd * gv.y + bv.y,
               (v.z - mu) * rstd * gv.z + bv.z, (v.w - mu) * rstd * gv.w + bv.w};
  *reinterpret_cast<float4*>(X + (size_t)row * DD + lane * 4) = o4;
}

__global__ __launch_bounds__(256) void k_ln4(const float* __restrict__ X,
                                             const float* __restrict__ g,
                                             const float* __restrict__ be,
                                             const int* __restrict__ lens,
                                             bf16* __restrict__ H) {
  int wid = threadIdx.x >> 6, lane = threadIdx.x & 63;
  int row = blockIdx.x * 4 + wid;
  int b = row >> 9, l = row & (LL - 1);
  if (l >= lens[b]) return;
  float4 v = *reinterpret_cast<const float4*>(X + (size_t)row * DD + lane * 4);
  float s = v.x + v.y + v.z + v.w;
  float q = v.x * v.x + v.y * v.y + v.z * v.z + v.w * v.w;
  #pragma unroll
  for (int o = 32; o > 0; o >>= 1) { s += __shfl_xor(s, o, 64); q += __shfl_xor(q, o, 64); }
  float mu = s * (1.f / DD);
  float rstd = rsqrtf(q * (1.f / DD) - mu * mu + 1e-5f);
  float4 gv = *reinterpret_cast<const float4*>(g + lane * 4);
  float4 bv = *reinterpret_cast<const float4*>(be + lane * 4);
  ushort4 o4;
  o4.x = f2bfbits((v.x - mu) * rstd * gv.x + bv.x);
  o4.y = f2bfbits((v.y - mu) * rstd * gv.y + bv.y);
  o4.z = f2bfbits((v.z - mu) * rstd * gv.z + bv.z);
  o4.w = f2bfbits((v.w - mu) * rstd * gv.w + bv.w);
  *reinterpret_cast<ushort4*>((ushort_t*)H + (size_t)row * DD + lane * 4) = o4;
}

__global__ __launch_bounds__(256) void k_cvtw(const float* __restrict__ w0, const float* __restrict__ w1,
                                              const float* __restrict__ w2, const float* __restrict__ w3,
                                              ushort_t* __restrict__ d) {
  int i = (blockIdx.x * 256 + threadIdx.x) * 4;
  const float* s; int off;
  if (i < 196608)      { s = w0; off = i; }
  else if (i < 262144) { s = w1; off = i - 196608; }
  else if (i < 393216) { s = w2; off = i - 262144; }
  else                 { s = w3; off = i - 393216; }
  float4 v = *reinterpret_cast<const float4*>(s + off);
  ushort4 o;
  o.x = f2bfbits(v.x); o.y = f2bfbits(v.y); o.z = f2bfbits(v.z); o.w = f2bfbits(v.w);
  *reinterpret_cast<ushort4*>(d + i) = o;
}

// -------- MFMA GEMM: MT x NT tile, BK=32, 4 waves, dbuf, conflict-free LDS --------
// LDS: L[row][c] = G[row][c ^ ((row>>1)&3)] (16B chunks); read slot
// 4*(row&1) + (fg ^ ((row>>1)&3)) -> 2-way per quarter = free.
template <int MT, int NT, bool GELU, bool RES, bool OUTBF16>
__global__ __launch_bounds__(256) void k_mgemm(const ushort_t* __restrict__ A,
                                               const ushort_t* __restrict__ Wb,
                                               const float* __restrict__ bias,
                                               const float* __restrict__ res,
                                               void* __restrict__ outp,
                                               const int* __restrict__ lens,
                                               int M, int Ndim, int Kdim) {
  constexpr int JF = (MT == 128) ? (NT / 32) : (NT / 64);      // n-frags per wave
  constexpr int AR = MT / 64, BR = NT / 64;                    // staging rounds
  int n0 = blockIdx.x * NT, m0 = blockIdx.y * MT;
  if ((m0 & (LL - 1)) >= lens[m0 >> 9]) return;                // whole tile padding
  __shared__ __align__(16) ushort_t As[2][MT * 32];
  __shared__ __align__(16) ushort_t Bs[2][NT * 32];
  int t = threadIdx.x, lane = t & 63, w = t >> 6;
  int wr = (MT == 128) ? (w >> 1) * 64 : 0;
  int wc = (MT == 128) ? (w & 1) * (NT / 2) : w * (NT / 4);
  int fr = lane & 15, fg = lane >> 4;

  int ca = lane & 3;
  const ushort_t* gA[AR];
  #pragma unroll
  for (int ra = 0; ra < AR; ra++) {
    int row = ra * 64 + (t >> 2);
    gA[ra] = A + (size_t)(m0 + row) * Kdim + ((ca ^ ((row >> 1) & 3)) << 3);
  }
  const ushort_t* gB[BR];
  #pragma unroll
  for (int rb = 0; rb < BR; rb++) {
    int row = rb * 64 + (t >> 2);
    gB[rb] = Wb + (size_t)(n0 + row) * Kdim + ((ca ^ ((row >> 1) & 3)) << 3);
  }

  f32x4 acc[4][JF];
  #pragma unroll
  for (int i = 0; i < 4; i++)
    #pragma unroll
    for (int j = 0; j < JF; j++) acc[i][j] = (f32x4){0.f, 0.f, 0.f, 0.f};

  int nk = Kdim >> 5;
  #define STAGE(bi, koff) { \
    _Pragma("unroll") for (int ra = 0; ra < AR; ra++) gl_lds16(gA[ra] + (koff), &As[bi][ra * 2048 + w * 512]); \
    _Pragma("unroll") for (int rb = 0; rb < BR; rb++) gl_lds16(gB[rb] + (koff), &Bs[bi][rb * 2048 + w * 512]); }

  STAGE(0, 0);
  __syncthreads();
  for (int kt = 0; kt < nk; kt++) {
    int cur = kt & 1;
    if (kt + 1 < nk) STAGE(cur ^ 1, (kt + 1) << 5);
    bf16x8 af[4], bfr[JF];
    #pragma unroll
    for (int i = 0; i < 4; i++) {
      int row = wr + i * 16 + fr;
      af[i] = *reinterpret_cast<const bf16x8*>(&As[cur][row * 32 + ((fg ^ ((row >> 1) & 3)) << 3)]);
    }
    #pragma unroll
    for (int j = 0; j < JF; j++) {
      int row = wc + j * 16 + fr;
      bfr[j] = *reinterpret_cast<const bf16x8*>(&Bs[cur][row * 32 + ((fg ^ ((row >> 1) & 3)) << 3)]);
    }
    #pragma unroll
    for (int i = 0; i < 4; i++)
      #pragma unroll
      for (int j = 0; j < JF; j++)
        acc[i][j] = MFMA(af[i], bfr[j], acc[i][j], 0, 0, 0);
    __syncthreads();
  }
  #undef STAGE

  #pragma unroll
  for (int i = 0; i < 4; i++) {
    int mbase = m0 + wr + i * 16 + fg * 4;
    #pragma unroll
    for (int j = 0; j < JF; j++) {
      int n = n0 + wc + j * 16 + fr;
      float bs = bias[n];
      #pragma unroll
      for (int r = 0; r < 4; r++) {
        int m = mbase + r;
        float v = acc[i][j][r] + bs;
        if (RES) v += res[(size_t)m * Ndim + n];
        if (GELU) v = 0.5f * v * (1.f + erff(v * 0.70710678118f));
        if (OUTBF16) ((ushort_t*)outp)[(size_t)m * Ndim + n] = f2bfbits(v);
        else         ((float*)outp)[(size_t)m * Ndim + n] = v;
      }
    }
  }
}

// -------- MFMA flash attention v6: 32KB LDS (128-k halves), exp2 softmax, defer-rescale --------
// grid (4 qchunks of 128, H, B); 512 thr / 8 waves, 16 q per wave; QKV [m][768].
__global__ __launch_bounds__(512) void k_mattn6(const ushort_t* __restrict__ QKV,
                                                const int* __restrict__ lens,
                                                ushort_t* __restrict__ O) {
  int b = blockIdx.z, h = blockIdx.y;
  int len = lens[b];
  int q0 = blockIdx.x * 128;
  if (q0 >= len) return;
  int t = threadIdx.x, lane = t & 63, w = t >> 6;
  int fr = lane & 15, fg = lane >> 4;
  __shared__ __align__(16) ushort_t Kh[8192];   // [128 k][64 d], chunk ^= (k&7)
  __shared__ __align__(16) ushort_t Vh[8192];   // [64 d][128 k], chunk(0..15) ^= S(d)&7

  const ushort_t* base = QKV + (size_t)b * LL * 768;
  int qw = q0 + w * 16;
  bool qact = qw < len;
  int q = qw + fr;

  const ushort_t* qp = base + (size_t)q * 768 + h * 64 + fg * 8;
  bf16x8 qf0 = *reinterpret_cast<const bf16x8*>(qp);
  bf16x8 qf1 = *reinterpret_cast<const bf16x8*>(qp + 32);

  const float SC = 0.125f * 1.44269504f;   // 1/sqrt(64) * log2(e): base-2 softmax
  f32x4 ot[4];
  #pragma unroll
  for (int df = 0; df < 4; df++) ot[df] = (f32x4){0.f, 0.f, 0.f, 0.f};
  float m_run = -1e30f, lsum = 0.f;

  for (int kb = 0; kb < len; kb += 128) {
    if (kb) __syncthreads();
    int lim = min(128, len - kb);
    // stage K half: LDS[k][c] = Kg[k][c ^ (k&7)]
    #pragma unroll
    for (int rr = 0; rr < 2; rr++) {
      if (rr * 64 >= lim) break;             // block-uniform
      int krow = rr * 64 + w * 8 + (lane >> 3);
      int gk = kb + krow; if (gk > len - 1) gk = len - 1;
      int ch = lane & 7;
      const ushort_t* src = base + (size_t)gk * 768 + 256 + h * 64 + ((ch ^ (krow & 7)) << 3);
      gl_lds16(src, &Kh[rr * 4096 + w * 512]);
    }
    // stage V^T half: coalesced 16B reads, scalar swizzled stores
    #pragma unroll
    for (int it = 0; it < 2; it++) {
      if (it * 64 >= lim) break;             // block-uniform (stale tail masked by p=0)
      int c = it * 512 + t;
      int k = c >> 3, dg = c & 7;
      int gk = kb + k; if (gk > len - 1) gk = len - 1;
      uint4 vv = *reinterpret_cast<const uint4*>(base + (size_t)gk * 768 + 512 + h * 64 + dg * 8);
      unsigned uu[4] = {vv.x, vv.y, vv.z, vv.w};
      #pragma unroll
      for (int j = 0; j < 4; j++) {
        int d0 = dg * 8 + j * 2, d1 = d0 + 1;
        int s0 = (d0 ^ (d0 >> 3)) & 7, s1 = (d1 ^ (d1 >> 3)) & 7;
        Vh[d0 * 128 + (((k >> 3) ^ s0) << 3) + (k & 7)] = (ushort_t)(uu[j] & 0xffff);
        Vh[d1 * 128 + (((k >> 3) ^ s1) << 3) + (k & 7)] = (ushort_t)(uu[j] >> 16);
      }
    }
    __syncthreads();

    if (qact) {
      for (int kt = 0; kt < lim; kt += 64) {
        // S^T = K·Q^T : k on (fg,r), q on fr
        f32x4 s[4];
        #pragma unroll
        for (int f = 0; f < 4; f++) {
          s[f] = (f32x4){0.f, 0.f, 0.f, 0.f};
          int krow = kt + f * 16 + fr;
          const ushort_t* kp0 = &Kh[krow * 64 + ((fg ^ (krow & 7)) << 3)];
          const ushort_t* kp1 = &Kh[krow * 64 + (((4 + fg) ^ (krow & 7)) << 3)];
          s[f] = MFMA(*reinterpret_cast<const bf16x8*>(kp0), qf0, s[f], 0, 0, 0);
          s[f] = MFMA(*reinterpret_cast<const bf16x8*>(kp1), qf1, s[f], 0, 0, 0);
        }
        int rem = lim - kt;
        #pragma unroll
        for (int f = 0; f < 4; f++)
          #pragma unroll
          for (int r = 0; r < 4; r++)
            s[f][r] = (f * 16 + fg * 4 + r < rem) ? s[f][r] * SC : -1e30f;
        float tm = -1e30f;
        #pragma unroll
        for (int f = 0; f < 4; f++)
          #pragma unroll
          for (int r = 0; r < 4; r++) tm = fmaxf(tm, s[f][r]);
        tm = fmaxf(tm, __shfl_xor(tm, 16, 64));
        tm = fmaxf(tm, __shfl_xor(tm, 32, 64));
        bool grow = tm > m_run;
        if (__any(grow)) {                    // defer-rescale (T13): skip when stable
          float m_new = grow ? tm : m_run;
          float corr = exp2f(m_run - m_new);
          lsum *= corr;
          #pragma unroll
          for (int df = 0; df < 4; df++)
            #pragma unroll
            for (int r = 0; r < 4; r++) ot[df][r] *= corr;
          m_run = m_new;
        }
        float ps = 0.f;
        #pragma unroll
        for (int f = 0; f < 4; f++)
          #pragma unroll
          for (int r = 0; r < 4; r++) {
            float p = exp2f(s[f][r] - m_run);
            s[f][r] = p; ps += p;
          }
        ps += __shfl_xor(ps, 16, 64);
        ps += __shfl_xor(ps, 32, 64);
        lsum += ps;
        // PV: O^T += Vh · P^T, P B-frag via shfl
        #pragma unroll
        for (int st = 0; st < 2; st++) {
          int fA = st * 2, fB = fA + 1;
          unsigned a0 = pkbf(s[fA][0], s[fA][1]), a1 = pkbf(s[fA][2], s[fA][3]);
          unsigned b0 = pkbf(s[fB][0], s[fB][1]), b1 = pkbf(s[fB][2], s[fB][3]);
          int sA = ((fg & 1) * 2) * 16 + fr;
          int sB = sA + 16;
          unsigned wa0 = __shfl(a0, sA, 64), wb0 = __shfl(b0, sA, 64);
          unsigned wa1 = __shfl(a1, sA, 64), wb1 = __shfl(b1, sA, 64);
          unsigned wa2 = __shfl(a0, sB, 64), wb2 = __shfl(b0, sB, 64);
          unsigned wa3 = __shfl(a1, sB, 64), wb3 = __shfl(b1, sB, 64);
          bool lo = fg < 2;
          U8 pf;
          pf.u[0] = lo ? wa0 : wb0; pf.u[1] = lo ? wa1 : wb1;
          pf.u[2] = lo ? wa2 : wb2; pf.u[3] = lo ? wa3 : wb3;
          int cb = (kt >> 3) + st * 4 + fg;   // 0..15
          #pragma unroll
          for (int df = 0; df < 4; df++) {
            int d = df * 16 + fr;
            int sd = (d ^ (d >> 3)) & 7;
            const ushort_t* vp = &Vh[d * 128 + ((cb ^ sd) << 3)];
            ot[df] = MFMA(*reinterpret_cast<const bf16x8*>(vp), pf.v, ot[df], 0, 0, 0);
          }
        }
      }
    }
  }

  if (q < len) {
    float linv = 1.f / lsum;
    #pragma unroll
    for (int df = 0; df < 4; df++) {
      ushort4 ov;
      ov.x = f2bfbits(ot[df][0] * linv);
      ov.y = f2bfbits(ot[df][1] * linv);
      ov.z = f2bfbits(ot[df][2] * linv);
      ov.w = f2bfbits(ot[df][3] * linv);
      *reinterpret_cast<ushort4*>(O + (size_t)(b * LL + q) * DD + h * 64 + df * 16 + fg * 4) = ov;
    }
  }
}

// -------- final attention pooling --------
__global__ __launch_bounds__(256) void k_pool(const float* __restrict__ X,
                                              const int* __restrict__ lens,
                                              bf16* __restrict__ pooled) {
  __shared__ float red[4];
  __shared__ float qs[DD];
  __shared__ float sc[LL];
  int b = blockIdx.x, t = threadIdx.x;
  int len = lens[b];
  const float* Xb = X + (size_t)b * LL * DD;
  qs[t] = Xb[(size_t)(len - 1) * DD + t];
  __syncthreads();
  for (int l = t; l < LL; l += 256) {
    float s = -1e30f;
    if (l < len) {
      const float4* xr = reinterpret_cast<const float4*>(Xb + (size_t)l * DD);
      const float4* qq = reinterpret_cast<const float4*>(qs);
      float a0 = 0, a1 = 0, a2 = 0, a3 = 0;
      for (int k4 = 0; k4 < 64; k4++) {
        float4 xv = xr[k4], qv = qq[k4];
        a0 += xv.x * qv.x; a1 += xv.y * qv.y; a2 += xv.z * qv.z; a3 += xv.w * qv.w;
      }
      s = (a0 + a1) + (a2 + a3);
    }
    sc[l] = s;
  }
  __syncthreads();
  float mx = fmaxf(sc[t], sc[t + 256]);
  #pragma unroll
  for (int off = 32; off > 0; off >>= 1) mx = fmaxf(mx, __shfl_down(mx, off, 64));
  __syncthreads();
  if ((t & 63) == 0) red[t >> 6] = mx;
  __syncthreads();
  mx = fmaxf(fmaxf(red[0], red[1]), fmaxf(red[2], red[3]));
  float e0 = (t < len) ? __expf(sc[t] - mx) : 0.f;
  float e1 = (t + 256 < len) ? __expf(sc[t + 256] - mx) : 0.f;
  float ssum = blk_sum(e0 + e1, red);
  float inv = 1.f / ssum;
  __syncthreads();
  sc[t] = e0 * inv; sc[t + 256] = e1 * inv;
  __syncthreads();
  float acc = 0.f;
  for (int l = 0; l < len; l++) acc += sc[l] * Xb[(size_t)l * DD + t];
  pooled[b * DD + t] = __float2bfloat16(acc);
}

// -------- classifier --------
__global__ __launch_bounds__(512) void k_cls(const ushort_t* __restrict__ POOL,
                                             const float* __restrict__ W,
                                             const float* __restrict__ bias,
                                             float* __restrict__ out) {
  int t = threadIdx.x, lane = t & 63, w = t >> 6;
  int fr = lane & 15, fg = lane >> 4;
  int n = blockIdx.x * 128 + w * 16 + fr;
  const float* wp = W + (size_t)n * DD + fg * 8;
  f32x4 acc[4];
  #pragma unroll
  for (int i = 0; i < 4; i++) acc[i] = (f32x4){0.f, 0.f, 0.f, 0.f};
  for (int k0 = 0; k0 < DD; k0 += 32) {
    float4 f0 = *reinterpret_cast<const float4*>(wp + k0);
    float4 f1 = *reinterpret_cast<const float4*>(wp + k0 + 4);
    U8 bfr;
    bfr.u[0] = pkbf(f0.x, f0.y); bfr.u[1] = pkbf(f0.z, f0.w);
    bfr.u[2] = pkbf(f1.x, f1.y); bfr.u[3] = pkbf(f1.z, f1.w);
    #pragma unroll
    for (int i = 0; i < 4; i++) {
      bf16x8 af = *reinterpret_cast<const bf16x8*>(POOL + (size_t)(i * 16 + fr) * DD + k0 + fg * 8);
      acc[i] = MFMA(af, bfr.v, acc[i], 0, 0, 0);
    }
  }
  float bs = bias[n];
  #pragma unroll
  for (int i = 0; i < 4; i++)
    #pragma unroll
    for (int r = 0; r < 4; r++)
      out[(size_t)(i * 16 + fg * 4 + r) * VV + n] = acc[i][r] + bs;
}

extern "C" void kernel_launch(void* const* d_in, const int* in_sizes, int n_in,
                              void* d_out, int out_size, void* d_ws, size_t ws_size,
                              hipStream_t stream) {
  const int*   tokens  = (const int*)d_in[0];
  const float* tok_emb = (const float*)d_in[2];
  const float* pos_emb = (const float*)d_in[3];
  const float* emb_g   = (const float*)d_in[4];
  const float* emb_b   = (const float*)d_in[5];
  const float* ln1_g   = (const float*)d_in[6];
  const float* ln1_b   = (const float*)d_in[7];
  const float* Wqkv    = (const float*)d_in[8];
  const float* bqkv    = (const float*)d_in[9];
  const float* Wo      = (const float*)d_in[10];
  const float* bo      = (const float*)d_in[11];
  const float* ln2_g   = (const float*)d_in[12];
  const float* ln2_b   = (const float*)d_in[13];
  const float* W1      = (const float*)d_in[14];
  const float* b1      = (const float*)d_in[15];
  const float* W2      = (const float*)d_in[16];
  const float* b2      = (const float*)d_in[17];
  const float* cls_W   = (const float*)d_in[22];
  const float* cls_b   = (const float*)d_in[23];

  char* ws = (char*)d_ws;
  float*    X    = (float*)ws;                         // 33,554,432 B
  ushort_t* QKV  = (ushort_t*)(ws + 33554432);         // 50,331,648 B (QKV [m][768] / FF1 [m][512])
  ushort_t* Hb   = (ushort_t*)(ws + 83886080);         // 16,777,216 B
  ushort_t* WB   = (ushort_t*)(ws + 100663296);        //  1,048,576 B per-layer weights bf16
  ushort_t* POOL = (ushort_t*)(ws + 101711872);        //     32,768 B
  int*      LEN  = (int*)(ws + 101744640);             //        256 B

  const int OFF_QKV = 0, OFF_WO = 196608, OFF_W1 = 262144, OFF_W2 = 393216;

  k_lens<<<BB, 256, 0, stream>>>(tokens, LEN);
  k_embed4<<<MM / 4, 256, 0, stream>>>(tokens, tok_emb, pos_emb, emb_g, emb_b, X);

  for (int e = 0; e < KK; e++) {
    k_cvtw<<<512, 256, 0, stream>>>(Wqkv + (size_t)e * 196608, Wo + (size_t)e * 65536,
                                    W1 + (size_t)e * 131072, W2 + (size_t)e * 131072, WB);
    k_ln4<<<MM / 4, 256, 0, stream>>>(X, ln1_g + e * DD, ln1_b + e * DD, LEN, (bf16*)Hb);
    k_mgemm<128, 256, false, false, true><<<dim3(3, 256), 256, 0, stream>>>(
        Hb, WB + OFF_QKV, bqkv + e * 3 * DD, nullptr, QKV, LEN, MM, 3 * DD, DD);
    k_mattn6<<<dim3(4, HH, BB), 512, 0, stream>>>(QKV, LEN, Hb);
    k_mgemm<64, 256, false, true, false><<<dim3(1, 512), 256, 0, stream>>>(
        Hb, WB + OFF_WO, bo + e * DD, X, X, LEN, MM, DD, DD);
    k_ln4<<<MM / 4, 256, 0, stream>>>(X, ln2_g + e * DD, ln2_b + e * DD, LEN, (bf16*)Hb);
    k_mgemm<128, 256, true, false, true><<<dim3(2, 256), 256, 0, stream>>>(
        Hb, WB + OFF_W1, b1 + e * FF, nullptr, QKV, LEN, MM, FF, DD);
    k_mgemm<64, 256, false, true, false><<<dim3(1, 512), 256, 0, stream>>>(
        QKV, WB + OFF_W2, b2 + e * DD, X, X, LEN, MM, DD, FF);
  }

  k_pool<<<BB, 256, 0, stream>>>(X, LEN, (bf16*)POOL);
  k_cls<<<dim3(VV / 128), 512, 0, stream>>>(POOL, cls_W, cls_b, (float*)d_out);
}